// Round 10
// baseline (8115.453 us; speedup 1.0000x reference)
//
#include <hip/hip_runtime.h>
#include <hip/hip_bf16.h>
#include <stdint.h>

typedef float  f32x4  __attribute__((ext_vector_type(4)));
typedef short  bf16x8 __attribute__((ext_vector_type(8)));
typedef unsigned int  u32;
typedef unsigned short u16;
typedef unsigned long long u64;

#define BS    64
#define SEQ   1024
#define HID   512

// ---------- helpers ----------
__device__ __forceinline__ u16 f2bf(float f) {
    u32 u = __float_as_uint(f);
    u32 r = (u + 0x7FFFu + ((u >> 16) & 1u)) >> 16;   // RNE
    return (u16)r;
}
__device__ __forceinline__ float bf2f(u16 h) {
    return __uint_as_float(((u32)h) << 16);
}
__device__ __forceinline__ u32 pk2(float a, float b) {
    return (u32)f2bf(a) | ((u32)f2bf(b) << 16);
}
__device__ __forceinline__ float sigm(float x)  { return 1.f / (1.f + __expf(-x)); }
__device__ __forceinline__ float tanh_(float x) { return 1.f - 2.f / (1.f + __expf(2.f * x)); }

// ---------- ws layout ----------
// [0, 2MB)            w4t  bf16 [2048][512]
// [2MB, +8KB)         b4   f32  [2048]
// [.., +256KB)        hf   u32  [2][4][16][512]  FAST inline-tagged words (L2 path)
// [.., +256KB)        hs   u32  [2][4][16][512]  SLOW inline-tagged words (MALL path)
// [.., +128KB)        cbuf f32  [4][16][512]
// [.., +128B)         claim u32 [8 chunks][4]    role counters per chunk launch
// [4MB, ...)          xp   bf16 [64*Tc][2048]
#define OFF_W4T   0
#define OFF_B4    (2u*1024*1024)
#define OFF_HF    (OFF_B4 + 8192)
#define OFF_HS    (OFF_HF + 262144)
#define OFF_CBUF  (OFF_HS + 262144)
#define OFF_CLAIM (OFF_CBUF + 131072)
#define OFF_XP    (4u*1024*1024)

// ---------- pack W / bias ----------
__global__ void pack_w(const float* __restrict__ Wi, const float* __restrict__ Wf,
                       const float* __restrict__ Wc, const float* __restrict__ Wo,
                       const float* __restrict__ bi, const float* __restrict__ bf_,
                       const float* __restrict__ bc, const float* __restrict__ bo,
                       u16* __restrict__ w4t, float* __restrict__ b4) {
    int n = blockIdx.x;                 // 0..2047
    int gate = n >> 9, c = n & 511;
    const float* W = (gate == 0) ? Wi : (gate == 1) ? Wf : (gate == 2) ? Wc : Wo;
    const float* B = (gate == 0) ? bi : (gate == 1) ? bf_ : (gate == 2) ? bc : bo;
    int k = threadIdx.x * 2;            // 2 per thread
    u32 v = pk2(W[(size_t)k * 512 + c], W[(size_t)(k + 1) * 512 + c]);
    *(u32*)&w4t[(size_t)n * 512 + k] = v;
    if (threadIdx.x == 0) b4[n] = B[c];
}

// ---------- projection GEMM:  xp[m][n] = bf16( x_row(m) . w4t[n] + b4[n] ) ----------
__global__ __launch_bounds__(256, 2)
void gemm_proj(const float* __restrict__ x, const u16* __restrict__ w4t,
               const float* __restrict__ b4, u16* __restrict__ xp,
               int t0, int Tc) {
    __shared__ __align__(16) u16 lA[128 * 64];
    __shared__ __align__(16) u16 lB[128 * 64];

    int ntb = blockIdx.x & 15;
    int mb  = blockIdx.x >> 4;
    int tps = Tc >> 7;                       // tiles per batch strip
    int bstrip = mb / tps, tb = mb % tps;
    const float* Abase = x + (size_t)(bstrip * SEQ + t0 + tb * 128) * 512;
    size_t xprow0 = (size_t)bstrip * Tc + tb * 128;
    int n0 = ntb * 128;

    int tid = threadIdx.x, lane = tid & 63, w = tid >> 6;
    int wm = w >> 1, wn = w & 1;

    f32x4 acc[4][4];
#pragma unroll
    for (int a = 0; a < 4; a++)
#pragma unroll
        for (int b = 0; b < 4; b++) acc[a][b] = (f32x4){0.f, 0.f, 0.f, 0.f};

    for (int kb = 0; kb < 8; kb++) {
        // stage A (fp32 -> bf16)
        {
            int row = tid >> 1, half = tid & 1;
            const float* src = Abase + (size_t)row * 512 + kb * 64 + half * 32;
            u32 tmp[16];
#pragma unroll
            for (int q = 0; q < 8; q++) {
                float4 f = *(const float4*)(src + q * 4);
                tmp[q * 2]     = pk2(f.x, f.y);
                tmp[q * 2 + 1] = pk2(f.z, f.w);
            }
            u16* dst = &lA[row * 64 + half * 32];
#pragma unroll
            for (int q = 0; q < 4; q++)
                *(uint4*)(dst + q * 8) = *(uint4*)&tmp[q * 4];
        }
        // stage B (already bf16)
        {
            int row = tid >> 1, kc = (tid & 1) * 32;
            const u16* src = w4t + (size_t)(n0 + row) * 512 + kb * 64 + kc;
            uint4 v0 = *(const uint4*)(src);
            uint4 v1 = *(const uint4*)(src + 8);
            uint4 v2 = *(const uint4*)(src + 16);
            uint4 v3 = *(const uint4*)(src + 24);
            u16* dst = &lB[row * 64 + kc];
            *(uint4*)(dst) = v0; *(uint4*)(dst + 8) = v1;
            *(uint4*)(dst + 16) = v2; *(uint4*)(dst + 24) = v3;
        }
        __syncthreads();
#pragma unroll
        for (int kt = 0; kt < 2; kt++) {
            bf16x8 a[4], bb[4];
#pragma unroll
            for (int mt = 0; mt < 4; mt++)
                a[mt] = *(const bf16x8*)&lA[(wm * 64 + mt * 16 + (lane & 15)) * 64 + kt * 32 + (lane >> 4) * 8];
#pragma unroll
            for (int nt = 0; nt < 4; nt++)
                bb[nt] = *(const bf16x8*)&lB[(wn * 64 + nt * 16 + (lane & 15)) * 64 + kt * 32 + (lane >> 4) * 8];
#pragma unroll
            for (int mt = 0; mt < 4; mt++)
#pragma unroll
                for (int nt = 0; nt < 4; nt++)
                    acc[mt][nt] = __builtin_amdgcn_mfma_f32_16x16x32_bf16(a[mt], bb[nt], acc[mt][nt], 0, 0, 0);
        }
        __syncthreads();
    }
    // epilogue: + bias, store bf16
#pragma unroll
    for (int nt = 0; nt < 4; nt++) {
        int n = n0 + wn * 64 + nt * 16 + (lane & 15);
        float bv = b4[n];
#pragma unroll
        for (int mt = 0; mt < 4; mt++)
#pragma unroll
            for (int r = 0; r < 4; r++) {
                size_t m = xprow0 + wm * 64 + mt * 16 + (lane >> 4) * 4 + r;
                xp[m * 2048 + n] = f2bf(acc[mt][nt][r] + bv);
            }
    }
}

// ---------- recurrence: XCD-claimed roles + dual-path inline-tagged exchange ----------
// 64 blocks; each reads HW_REG_XCC_ID and claims a role (gid 0..3, q 0..7) from an
// atomic table, preferring group == own XCD (XCDs 0-3 primary; 4-7 sleep then fill;
// unclaimed exit). With near-balanced dispatch each group's 8 WGs share ONE XCD+L2.
// Exchange word = (h_bf16<<16)|step_tag (R3-proven), double-buffered by t&1:
//   FAST: volatile stores/loads through the shared XCD L2 (valid only same-XCD;
//         stale/torn reads simply fail the tag check).
//   SLOW: agent-scope atomics via MALL (always correct) — alternating sweeps.
// ADDRESS UNITS (R9 hang root cause): consumer poll in u64 units uses
// buf<<14 + gid<<12 (+tid); producer publish in u32 units MUST be the same region:
// ((t&1)*4 + gid) << 13. R9 had buf<<14 in u32 units -> regions collided -> hang.
__global__ __launch_bounds__(256, 1)
void lstm_rec(const float* __restrict__ U0, const float* __restrict__ U1,
              const float* __restrict__ U2, const float* __restrict__ U3,
              const u16* __restrict__ xp, float* __restrict__ out,
              u32* __restrict__ hf, u32* __restrict__ hs,
              float* __restrict__ cbuf, u32* __restrict__ claim,
              int t0, int Tc, int ci) {
    const int tid = threadIdx.x;

    // ---- role claim ----
    __shared__ int role_s;
    if (tid == 0) {
        u32 xcc;
        asm volatile("s_getreg_b32 %0, hwreg(HW_REG_XCC_ID)" : "=s"(xcc));
        xcc &= 7u;
        if (xcc >= 4u) {            // secondary XCDs: let primaries claim first
            for (int i = 0; i < 2; i++) __builtin_amdgcn_s_sleep(127);
        }
        int r = -1;
        u32* cnt = claim + ci * 4;
        for (int a = 0; a < 4 && r < 0; a++) {
            int g = ((int)(xcc & 3u) + a) & 3;
            u32 s = __hip_atomic_fetch_add(&cnt[g], 1u, __ATOMIC_RELAXED,
                                           __HIP_MEMORY_SCOPE_AGENT);
            if (s < 8u) r = g * 8 + (int)s;
        }
        role_s = r;
    }
    __syncthreads();
    const int role = role_s;
    if (role < 0) return;
    const int gid = role >> 3;
    const int q   = role & 7;

    const int w = tid >> 6, lane = tid & 63;
    const int col16 = lane & 15;
    const int krow  = lane >> 4;                  // 0..3
    const int mycol = q * 64 + w * 16 + col16;    // h-col 0..511

    __shared__ __align__(16) u16 h_lds[2][16 * 512];   // double-buffered, XOR-swizzled

    // ---- persistent U fragments: ub[kt][gate] ----
    const float* Ug[4] = {U0, U1, U2, U3};
    bf16x8 ub[16][4];
#pragma unroll
    for (int kt = 0; kt < 16; kt++) {
        int kbase = kt * 32 + krow * 8;
#pragma unroll
        for (int g = 0; g < 4; g++) {
            union { u16 sh[8]; bf16x8 v; } uu;
#pragma unroll
            for (int j = 0; j < 8; j++)
                uu.sh[j] = f2bf(Ug[g][(size_t)(kbase + j) * 512 + mycol]);
            ub[kt][g] = uu.v;
        }
    }

    // ---- c state in registers (rows krow*4+r) ----
    float c[4];
    if (t0 == 0) {
        c[0] = c[1] = c[2] = c[3] = 0.f;
    } else {
#pragma unroll
        for (int r = 0; r < 4; r++)
            c[r] = cbuf[((size_t)gid * 16 + krow * 4 + r) * 512 + mycol];
    }

    for (int tl = 0; tl < Tc; tl++) {
        const int t = t0 + tl;
        const u32 te = (u32)t & 0xFFFFu;

        // ---- xp prefetch first: HBM latency overlaps the poll below ----
        u16 xr[4][4];
#pragma unroll
        for (int g = 0; g < 4; g++)
#pragma unroll
            for (int r = 0; r < 4; r++)
                xr[g][r] = xp[(size_t)((gid * 16 + krow * 4 + r) * Tc + tl) * 2048
                              + g * 512 + mycol];

        // ---- dual-path inline-tagged poll of h_{t-1} ----
        // thread tid owns col pair {2tid,2tid+1} x rows 0..15 (u64 at row*256+tid;
        // per instruction lanes are 8B apart = fully coalesced)
        u64 v[16];
        {
            const u64 pbase = (((u64)((t + 1) & 1)) << 14) + ((u64)gid << 12) + (u64)tid;
            const volatile u64* fsrc = (const volatile u64*)hf + pbase;
            const u64*          ssrc = (const u64*)hs + pbase;
            for (int sp = 0;; ++sp) {
                if ((sp & 1) == 0) {
#pragma unroll
                    for (int j = 0; j < 16; j++)
                        v[j] = fsrc[j * 256];
                } else {
#pragma unroll
                    for (int j = 0; j < 16; j++)
                        v[j] = __hip_atomic_load(ssrc + j * 256, __ATOMIC_RELAXED,
                                                 __HIP_MEMORY_SCOPE_AGENT);
                }
                u32 bad = 0;
#pragma unroll
                for (int j = 0; j < 16; j++) {
                    bad |= (((u32)v[j]) ^ te) & 0xFFFFu;
                    bad |= (((u32)(v[j] >> 32)) ^ te) & 0xFFFFu;
                }
                if (!bad) break;
            }
        }

        // ---- stage to LDS (buffer t&1), swizzled ----
        u16* hl = &h_lds[t & 1][0];
#pragma unroll
        for (int j = 0; j < 16; j++) {
            u32 packed = ((u32)v[j] >> 16) | ((u32)(v[j] >> 32) & 0xFFFF0000u);
            u32 byte = ((u32)(j * 1024) + (u32)(tid * 4)) ^ ((u32)(j & 7) << 4);
            *(u32*)((char*)hl + byte) = packed;
        }
        __syncthreads();

        // ---- z = h @ U : 64 MFMAs/wave, gates in-register ----
        f32x4 acc[4];
#pragma unroll
        for (int g = 0; g < 4; g++) acc[g] = (f32x4){0.f, 0.f, 0.f, 0.f};
#pragma unroll
        for (int kt = 0; kt < 16; kt++) {
            u32 byte = ((u32)(col16 * 1024) + (u32)(kt * 64) + (u32)(krow * 16))
                       ^ ((u32)(col16 & 7) << 4);
            bf16x8 af = *(const bf16x8*)((const char*)hl + byte);
#pragma unroll
            for (int g = 0; g < 4; g++)
                acc[g] = __builtin_amdgcn_mfma_f32_16x16x32_bf16(af, ub[kt][g], acc[g], 0, 0, 0);
        }

        // ---- gates ----
        float hv[4];
#pragma unroll
        for (int r = 0; r < 4; r++) {
            float zi = acc[0][r] + bf2f(xr[0][r]);
            float zf = acc[1][r] + bf2f(xr[1][r]);
            float zg = acc[2][r] + bf2f(xr[2][r]);
            float zo = acc[3][r] + bf2f(xr[3][r]);
            float iv = fmaxf(zi, 0.f), fv = fmaxf(zf, 0.f);
            float gv = tanh_(zg), ov = sigm(zo);
            c[r] = fv * c[r] + iv * gv;
            hv[r] = ov * tanh_(c[r]);
        }

        // ---- publish tagged h_t to BOTH paths (no drain, no flag) ----
        // base in u32 units == poll region: (t&1)*32768 + gid*8192  (R8-proven form)
        {
            const u32 tag = (u32)((t + 1) & 0xFFFF);
            u32 base = (((u32)(t & 1)) * 4 + (u32)gid) << 13;   // u32 words
#pragma unroll
            for (int r = 0; r < 4; r++) {
                int row = krow * 4 + r;
                u32 word = ((u32)f2bf(hv[r]) << 16) | tag;
                u32 idx = base + (u32)row * 512 + (u32)mycol;
                ((volatile u32*)hf)[idx] = word;                  // fast: shared-L2 path
                __hip_atomic_store(hs + idx, word, __ATOMIC_RELAXED,
                                   __HIP_MEMORY_SCOPE_AGENT);     // slow: MALL path
            }
        }

        // ---- output stores (off critical path) ----
#pragma unroll
        for (int r = 0; r < 4; r++)
            out[(size_t)((gid * 16 + krow * 4 + r) * SEQ + t) * 512 + mycol] = hv[r];
    }

    // save c for next chunk
#pragma unroll
    for (int r = 0; r < 4; r++)
        cbuf[((size_t)gid * 16 + krow * 4 + r) * 512 + mycol] = c[r];
}

// ---------- launch ----------
extern "C" void kernel_launch(void* const* d_in, const int* in_sizes, int n_in,
                              void* d_out, int out_size, void* d_ws, size_t ws_size,
                              hipStream_t stream) {
    const float* x  = (const float*)d_in[0];
    const float* Wg[4] = {(const float*)d_in[1], (const float*)d_in[4],
                          (const float*)d_in[7], (const float*)d_in[10]};
    const float* Ug[4] = {(const float*)d_in[2], (const float*)d_in[5],
                          (const float*)d_in[8], (const float*)d_in[11]};
    const float* Bg[4] = {(const float*)d_in[3], (const float*)d_in[6],
                          (const float*)d_in[9], (const float*)d_in[12]};
    float* out = (float*)d_out;

    char* ws = (char*)d_ws;
    u16*   w4t   = (u16*)(ws + OFF_W4T);
    float* b4    = (float*)(ws + OFF_B4);
    u32*   hf    = (u32*)(ws + OFF_HF);
    u32*   hs    = (u32*)(ws + OFF_HS);
    float* cbuf  = (float*)(ws + OFF_CBUF);
    u32*   claim = (u32*)(ws + OFF_CLAIM);
    u16*   xp    = (u16*)(ws + OFF_XP);

    // pick chunk length that fits ws
    int Tc = 128;
    for (int c = 1024; c >= 128; c >>= 1)
        if ((size_t)OFF_XP + (size_t)BS * c * 2048 * 2 <= ws_size) { Tc = c; break; }

    // zero both tagged buffers (tag 0 == "h_{-1}=0 ready") + claim table
    hipMemsetAsync(ws + OFF_HF, 0, 524288, stream);
    hipMemsetAsync(ws + OFF_CLAIM, 0, 128, stream);

    pack_w<<<2048, 256, 0, stream>>>(Wg[0], Wg[1], Wg[2], Wg[3],
                                     Bg[0], Bg[1], Bg[2], Bg[3], w4t, b4);

    int ci = 0;
    for (int t0 = 0; t0 < SEQ; t0 += Tc, ci++) {
        dim3 ggrid((unsigned)(BS * (Tc / 128) * 16));
        gemm_proj<<<ggrid, 256, 0, stream>>>(x, w4t, b4, xp, t0, Tc);
        lstm_rec<<<64, 256, 0, stream>>>(Ug[0], Ug[1], Ug[2], Ug[3],
                                         xp, out, hf, hs, cbuf, claim, t0, Tc, ci);
    }
}

// Round 11
// 4185.961 us; speedup vs baseline: 1.9387x; 1.9387x over previous
//
#include <hip/hip_runtime.h>
#include <hip/hip_bf16.h>
#include <stdint.h>

typedef float  f32x4  __attribute__((ext_vector_type(4)));
typedef short  bf16x8 __attribute__((ext_vector_type(8)));
typedef unsigned int  u32;
typedef unsigned short u16;
typedef unsigned long long u64;

#define BS    64
#define SEQ   1024
#define HID   512

// ---------- helpers ----------
__device__ __forceinline__ u16 f2bf(float f) {
    u32 u = __float_as_uint(f);
    u32 r = (u + 0x7FFFu + ((u >> 16) & 1u)) >> 16;   // RNE
    return (u16)r;
}
__device__ __forceinline__ float bf2f(u16 h) {
    return __uint_as_float(((u32)h) << 16);
}
__device__ __forceinline__ u32 pk2(float a, float b) {
    return (u32)f2bf(a) | ((u32)f2bf(b) << 16);
}
__device__ __forceinline__ float sigm(float x)  { return 1.f / (1.f + __expf(-x)); }
__device__ __forceinline__ float tanh_(float x) { return 1.f - 2.f / (1.f + __expf(2.f * x)); }

// ---------- ws layout ----------
// [0, 2MB)            w4t  bf16 [2048][512]
// [2MB, +8KB)         b4   f32  [2048]
// [.., +256KB)        hb   u64-viewed [2][4][16][512] u32 words = (h_bf16<<16)|tag
// [.., +4KB)          tg   u32  [4][16]  hint tags (64B/group line, q=0..7 used)
// [.., +128KB)        cbuf f32  [4][16][512]
// [4MB, ...)          xp   bf16 [64*Tc][2048]
#define OFF_W4T   0
#define OFF_B4    (2u*1024*1024)
#define OFF_HB    (OFF_B4 + 8192)
#define OFF_TG    (OFF_HB + 262144)
#define OFF_CBUF  (OFF_TG + 4096)
#define OFF_XP    (4u*1024*1024)

// ---------- pack W / bias ----------
__global__ void pack_w(const float* __restrict__ Wi, const float* __restrict__ Wf,
                       const float* __restrict__ Wc, const float* __restrict__ Wo,
                       const float* __restrict__ bi, const float* __restrict__ bf_,
                       const float* __restrict__ bc, const float* __restrict__ bo,
                       u16* __restrict__ w4t, float* __restrict__ b4) {
    int n = blockIdx.x;                 // 0..2047
    int gate = n >> 9, c = n & 511;
    const float* W = (gate == 0) ? Wi : (gate == 1) ? Wf : (gate == 2) ? Wc : Wo;
    const float* B = (gate == 0) ? bi : (gate == 1) ? bf_ : (gate == 2) ? bc : bo;
    int k = threadIdx.x * 2;            // 2 per thread
    u32 v = pk2(W[(size_t)k * 512 + c], W[(size_t)(k + 1) * 512 + c]);
    *(u32*)&w4t[(size_t)n * 512 + k] = v;
    if (threadIdx.x == 0) b4[n] = B[c];
}

// ---------- projection GEMM:  xp[m][n] = bf16( x_row(m) . w4t[n] + b4[n] ) ----------
__global__ __launch_bounds__(256, 2)
void gemm_proj(const float* __restrict__ x, const u16* __restrict__ w4t,
               const float* __restrict__ b4, u16* __restrict__ xp,
               int t0, int Tc) {
    __shared__ __align__(16) u16 lA[128 * 64];
    __shared__ __align__(16) u16 lB[128 * 64];

    int ntb = blockIdx.x & 15;
    int mb  = blockIdx.x >> 4;
    int tps = Tc >> 7;                       // tiles per batch strip
    int bstrip = mb / tps, tb = mb % tps;
    const float* Abase = x + (size_t)(bstrip * SEQ + t0 + tb * 128) * 512;
    size_t xprow0 = (size_t)bstrip * Tc + tb * 128;
    int n0 = ntb * 128;

    int tid = threadIdx.x, lane = tid & 63, w = tid >> 6;
    int wm = w >> 1, wn = w & 1;

    f32x4 acc[4][4];
#pragma unroll
    for (int a = 0; a < 4; a++)
#pragma unroll
        for (int b = 0; b < 4; b++) acc[a][b] = (f32x4){0.f, 0.f, 0.f, 0.f};

    for (int kb = 0; kb < 8; kb++) {
        // stage A (fp32 -> bf16)
        {
            int row = tid >> 1, half = tid & 1;
            const float* src = Abase + (size_t)row * 512 + kb * 64 + half * 32;
            u32 tmp[16];
#pragma unroll
            for (int q = 0; q < 8; q++) {
                float4 f = *(const float4*)(src + q * 4);
                tmp[q * 2]     = pk2(f.x, f.y);
                tmp[q * 2 + 1] = pk2(f.z, f.w);
            }
            u16* dst = &lA[row * 64 + half * 32];
#pragma unroll
            for (int q = 0; q < 4; q++)
                *(uint4*)(dst + q * 8) = *(uint4*)&tmp[q * 4];
        }
        // stage B (already bf16)
        {
            int row = tid >> 1, kc = (tid & 1) * 32;
            const u16* src = w4t + (size_t)(n0 + row) * 512 + kb * 64 + kc;
            uint4 v0 = *(const uint4*)(src);
            uint4 v1 = *(const uint4*)(src + 8);
            uint4 v2 = *(const uint4*)(src + 16);
            uint4 v3 = *(const uint4*)(src + 24);
            u16* dst = &lB[row * 64 + kc];
            *(uint4*)(dst) = v0; *(uint4*)(dst + 8) = v1;
            *(uint4*)(dst + 16) = v2; *(uint4*)(dst + 24) = v3;
        }
        __syncthreads();
#pragma unroll
        for (int kt = 0; kt < 2; kt++) {
            bf16x8 a[4], bb[4];
#pragma unroll
            for (int mt = 0; mt < 4; mt++)
                a[mt] = *(const bf16x8*)&lA[(wm * 64 + mt * 16 + (lane & 15)) * 64 + kt * 32 + (lane >> 4) * 8];
#pragma unroll
            for (int nt = 0; nt < 4; nt++)
                bb[nt] = *(const bf16x8*)&lB[(wn * 64 + nt * 16 + (lane & 15)) * 64 + kt * 32 + (lane >> 4) * 8];
#pragma unroll
            for (int mt = 0; mt < 4; mt++)
#pragma unroll
                for (int nt = 0; nt < 4; nt++)
                    acc[mt][nt] = __builtin_amdgcn_mfma_f32_16x16x32_bf16(a[mt], bb[nt], acc[mt][nt], 0, 0, 0);
        }
        __syncthreads();
    }
    // epilogue: + bias, store bf16
#pragma unroll
    for (int nt = 0; nt < 4; nt++) {
        int n = n0 + wn * 64 + nt * 16 + (lane & 15);
        float bv = b4[n];
#pragma unroll
        for (int mt = 0; mt < 4; mt++)
#pragma unroll
            for (int r = 0; r < 4; r++) {
                size_t m = xprow0 + wm * 64 + mt * 16 + (lane >> 4) * 4 + r;
                xp[m * 2048 + n] = f2bf(acc[mt][nt][r] + bv);
            }
    }
}

// ---------- recurrence: hint tag + inline-tagged data (no producer drain) ----------
// 32 WGs x 256 threads: gid = blockIdx>>3 (16 batch rows), q = blockIdx&7 (64 h-cols).
// Wave w owns h-cols [q*64+w*16,+16) for all 4 gates; U slice persistent ub[16][4].
// Publish (fire-and-forget, all relaxed agent atomics): 4 inline-tagged data words
// ((h_bf16<<16)|t+1, R3-proven layout) then tid0 stores hint tg[gid*16+q]=t+1 —
// NO drain/barrier between them. Consume: poll the 32B hint line (all 8 q's >= t),
// then read 16 u64 of data and VALIDATE inline tags; re-sweep if a producer's data
// lagged its hint (rare; waves publish within ~100cy of the shared barrier).
// Induction (R3): buffer read at step t is next overwritten at t+2, and any producer
// is at most 1 step ahead of any consumer -> exact-tag validate + '>=' hint are safe;
// monotonic tags -> deadlock-free, chunk- and graph-replay-safe.
__global__ __launch_bounds__(256, 1)
void lstm_rec(const float* __restrict__ U0, const float* __restrict__ U1,
              const float* __restrict__ U2, const float* __restrict__ U3,
              const u16* __restrict__ xp, float* __restrict__ out,
              u64* __restrict__ hb, u32* __restrict__ tg,
              float* __restrict__ cbuf, int t0, int Tc) {
    const int gid = blockIdx.x >> 3;
    const int q   = blockIdx.x & 7;
    const int tid = threadIdx.x;
    const int w = tid >> 6, lane = tid & 63;
    const int col16 = lane & 15;
    const int krow  = lane >> 4;                  // 0..3
    const int mycol = q * 64 + w * 16 + col16;    // h-col 0..511

    __shared__ __align__(16) u16 h_lds[2][16 * 512];   // double-buffered, XOR-swizzled

    // ---- persistent U fragments: ub[kt][gate] ----
    const float* Ug[4] = {U0, U1, U2, U3};
    bf16x8 ub[16][4];
#pragma unroll
    for (int kt = 0; kt < 16; kt++) {
        int kbase = kt * 32 + krow * 8;
#pragma unroll
        for (int g = 0; g < 4; g++) {
            union { u16 sh[8]; bf16x8 v; } uu;
#pragma unroll
            for (int j = 0; j < 8; j++)
                uu.sh[j] = f2bf(Ug[g][(size_t)(kbase + j) * 512 + mycol]);
            ub[kt][g] = uu.v;
        }
    }

    // ---- c state in registers (rows krow*4+r) ----
    float c[4];
    if (t0 == 0) {
        c[0] = c[1] = c[2] = c[3] = 0.f;
    } else {
#pragma unroll
        for (int r = 0; r < 4; r++)
            c[r] = cbuf[((size_t)gid * 16 + krow * 4 + r) * 512 + mycol];
    }

    const u64* tagp = (const u64*)(tg + gid * 16);

    for (int tl = 0; tl < Tc; tl++) {
        const int t = t0 + tl;

        // ---- xp prefetch first: HBM latency overlaps poll + data read ----
        u16 xr[4][4];
#pragma unroll
        for (int g = 0; g < 4; g++)
#pragma unroll
            for (int r = 0; r < 4; r++)
                xr[g][r] = xp[(size_t)((gid * 16 + krow * 4 + r) * Tc + tl) * 2048
                              + g * 512 + mycol];

        // ---- poll 32B hint line until all 8 producers of h_{t-1} published ----
        {
            const u32 te = (u32)t;
            for (;;) {
                u64 a0 = __hip_atomic_load(tagp + 0, __ATOMIC_RELAXED, __HIP_MEMORY_SCOPE_AGENT);
                u64 a1 = __hip_atomic_load(tagp + 1, __ATOMIC_RELAXED, __HIP_MEMORY_SCOPE_AGENT);
                u64 a2 = __hip_atomic_load(tagp + 2, __ATOMIC_RELAXED, __HIP_MEMORY_SCOPE_AGENT);
                u64 a3 = __hip_atomic_load(tagp + 3, __ATOMIC_RELAXED, __HIP_MEMORY_SCOPE_AGENT);
                bool ok = ((u32)a0 >= te) & ((u32)(a0 >> 32) >= te)
                        & ((u32)a1 >= te) & ((u32)(a1 >> 32) >= te)
                        & ((u32)a2 >= te) & ((u32)(a2 >> 32) >= te)
                        & ((u32)a3 >= te) & ((u32)(a3 >> 32) >= te);
                if (ok) break;
            }
        }

        // ---- read h_{t-1} data + inline-tag validate (usually 1 sweep) ----
        // thread tid owns cols {2tid,2tid+1} x rows 0..15 (u64 at j*256+tid; per
        // instruction lanes 8B apart = fully coalesced). R3-proven addressing.
        u64 v[16];
        {
            const u64* src = hb + (((size_t)((t + 1) & 1)) << 14) + ((size_t)gid << 12) + tid;
            const u32 te = (u32)t & 0xFFFFu;
            for (;;) {
#pragma unroll
                for (int j = 0; j < 16; j++)
                    v[j] = __hip_atomic_load(src + j * 256, __ATOMIC_RELAXED,
                                             __HIP_MEMORY_SCOPE_AGENT);
                u32 bad = 0;
#pragma unroll
                for (int j = 0; j < 16; j++) {
                    bad |= (((u32)v[j]) ^ te) & 0xFFFFu;
                    bad |= (((u32)(v[j] >> 32)) ^ te) & 0xFFFFu;
                }
                if (!bad) break;
            }
        }

        // ---- stage to LDS (buffer t&1), swizzled ----
        u16* hl = &h_lds[t & 1][0];
#pragma unroll
        for (int j = 0; j < 16; j++) {
            u32 packed = ((u32)v[j] >> 16) | ((u32)(v[j] >> 32) & 0xFFFF0000u);
            u32 byte = ((u32)(j * 1024) + (u32)(tid * 4)) ^ ((u32)(j & 7) << 4);
            *(u32*)((char*)hl + byte) = packed;
        }
        __syncthreads();     // the single per-step barrier

        // ---- z = h @ U : 64 MFMAs/wave, gates in-register ----
        f32x4 acc[4];
#pragma unroll
        for (int g = 0; g < 4; g++) acc[g] = (f32x4){0.f, 0.f, 0.f, 0.f};
#pragma unroll
        for (int kt = 0; kt < 16; kt++) {
            u32 byte = ((u32)(col16 * 1024) + (u32)(kt * 64) + (u32)(krow * 16))
                       ^ ((u32)(col16 & 7) << 4);
            bf16x8 af = *(const bf16x8*)((const char*)hl + byte);
#pragma unroll
            for (int g = 0; g < 4; g++)
                acc[g] = __builtin_amdgcn_mfma_f32_16x16x32_bf16(af, ub[kt][g], acc[g], 0, 0, 0);
        }

        // ---- gates ----
        float hv[4];
#pragma unroll
        for (int r = 0; r < 4; r++) {
            float zi = acc[0][r] + bf2f(xr[0][r]);
            float zf = acc[1][r] + bf2f(xr[1][r]);
            float zg = acc[2][r] + bf2f(xr[2][r]);
            float zo = acc[3][r] + bf2f(xr[3][r]);
            float iv = fmaxf(zi, 0.f), fv = fmaxf(zf, 0.f);
            float gv = tanh_(zg), ov = sigm(zo);
            c[r] = fv * c[r] + iv * gv;
            hv[r] = ov * tanh_(c[r]);
        }

        // ---- publish: inline-tagged data, then hint — NO drain ----
        {
            const u32 tag = (u32)((t + 1) & 0xFFFF);
            u32* dst = (u32*)(hb + (((size_t)(t & 1) * 4 + gid) << 12));
#pragma unroll
            for (int r = 0; r < 4; r++) {
                int row = krow * 4 + r;
                u32 word = ((u32)f2bf(hv[r]) << 16) | tag;
                __hip_atomic_store(dst + row * 512 + mycol, word, __ATOMIC_RELAXED,
                                   __HIP_MEMORY_SCOPE_AGENT);
            }
            if (tid == 0)
                __hip_atomic_store(tg + gid * 16 + q, (u32)(t + 1),
                                   __ATOMIC_RELAXED, __HIP_MEMORY_SCOPE_AGENT);
        }

        // ---- output stores (off critical path) ----
#pragma unroll
        for (int r = 0; r < 4; r++)
            out[(size_t)((gid * 16 + krow * 4 + r) * SEQ + t) * 512 + mycol] = hv[r];
    }

    // save c for next chunk
#pragma unroll
    for (int r = 0; r < 4; r++)
        cbuf[((size_t)gid * 16 + krow * 4 + r) * 512 + mycol] = c[r];
}

// ---------- launch ----------
extern "C" void kernel_launch(void* const* d_in, const int* in_sizes, int n_in,
                              void* d_out, int out_size, void* d_ws, size_t ws_size,
                              hipStream_t stream) {
    const float* x  = (const float*)d_in[0];
    const float* Wg[4] = {(const float*)d_in[1], (const float*)d_in[4],
                          (const float*)d_in[7], (const float*)d_in[10]};
    const float* Ug[4] = {(const float*)d_in[2], (const float*)d_in[5],
                          (const float*)d_in[8], (const float*)d_in[11]};
    const float* Bg[4] = {(const float*)d_in[3], (const float*)d_in[6],
                          (const float*)d_in[9], (const float*)d_in[12]};
    float* out = (float*)d_out;

    char* ws = (char*)d_ws;
    u16*   w4t   = (u16*)(ws + OFF_W4T);
    float* b4    = (float*)(ws + OFF_B4);
    u64*   hb    = (u64*)(ws + OFF_HB);
    u32*   tg    = (u32*)(ws + OFF_TG);
    float* cbuf  = (float*)(ws + OFF_CBUF);
    u16*   xp    = (u16*)(ws + OFF_XP);

    // pick chunk length that fits ws
    int Tc = 128;
    for (int c = 1024; c >= 128; c >>= 1)
        if ((size_t)OFF_XP + (size_t)BS * c * 2048 * 2 <= ws_size) { Tc = c; break; }

    // zero inline-tagged data (tag 0 == "h_{-1}=0 ready") + hint tags
    hipMemsetAsync(ws + OFF_HB, 0, 262144 + 4096, stream);

    pack_w<<<2048, 256, 0, stream>>>(Wg[0], Wg[1], Wg[2], Wg[3],
                                     Bg[0], Bg[1], Bg[2], Bg[3], w4t, b4);

    for (int t0 = 0; t0 < SEQ; t0 += Tc) {
        dim3 ggrid((unsigned)(BS * (Tc / 128) * 16));
        gemm_proj<<<ggrid, 256, 0, stream>>>(x, w4t, b4, xp, t0, Tc);
        lstm_rec<<<32, 256, 0, stream>>>(Ug[0], Ug[1], Ug[2], Ug[3],
                                         xp, out, hb, tg, cbuf, t0, Tc);
    }
}